// Round 1
// baseline (960.357 us; speedup 1.0000x reference)
//
#include <hip/hip_runtime.h>

#define N 1024
#define D 64

// ---------------- K1: LN1 + QKV projection ----------------
__global__ __launch_bounds__(64) void k_ln1_qkv(
    const float* __restrict__ feats, const float* __restrict__ g, const float* __restrict__ b,
    const float* __restrict__ qkv_w, float* __restrict__ xn, float* __restrict__ qkv) {
  const int i = blockIdx.x, t = threadIdx.x;
  float v = feats[i * D + t];
  float s = v;
#pragma unroll
  for (int off = 32; off; off >>= 1) s += __shfl_xor(s, off);
  const float m = s * (1.0f / 64.0f);
  const float dv = v - m;
  float vs = dv * dv;
#pragma unroll
  for (int off = 32; off; off >>= 1) vs += __shfl_xor(vs, off);
  const float var = vs * (1.0f / 64.0f);
  const float xv = dv * rsqrtf(var + 1e-5f) * g[t] + b[t];
  xn[i * D + t] = xv;
  __shared__ float xs[D];
  xs[t] = xv;
  __syncthreads();
#pragma unroll
  for (int c = 0; c < 3; ++c) {
    const int col = t + c * 64;
    float acc = 0.f;
#pragma unroll 8
    for (int k = 0; k < D; ++k) acc += xs[k] * qkv_w[k * 192 + col];
    qkv[i * 192 + col] = acc;
  }
}

// ---------------- K2: attention + mean-attn + out-proj + residual ----------------
__global__ __launch_bounds__(256) void k_attn(
    const float* __restrict__ qkv, const float* __restrict__ xn,
    const float* __restrict__ out_w, const float* __restrict__ out_b,
    float* __restrict__ x1, float* __restrict__ meanattn) {
  const int i = blockIdx.x, t = threadIdx.x;
  const int lane = t & 63, w = t >> 6;
  __shared__ float sc[4][N];
  __shared__ float qi[D];
  __shared__ float wred[4][4];
  __shared__ float hstat[8];  // m[0..3], l[4..7]
  __shared__ float red[256];
  __shared__ float msgv[64];
  if (t < D) qi[t] = qkv[i * 192 + t];
  __syncthreads();
  float lm[4] = {-1e30f, -1e30f, -1e30f, -1e30f};
  for (int j = t; j < N; j += 256) {
    const float* kj = &qkv[j * 192 + 64];
    float a0 = 0.f, a1 = 0.f, a2 = 0.f, a3 = 0.f;
#pragma unroll
    for (int d = 0; d < 16; ++d) {
      a0 += qi[d] * kj[d];
      a1 += qi[16 + d] * kj[16 + d];
      a2 += qi[32 + d] * kj[32 + d];
      a3 += qi[48 + d] * kj[48 + d];
    }
    a0 *= 0.125f; a1 *= 0.125f; a2 *= 0.125f; a3 *= 0.125f;
    sc[0][j] = a0; sc[1][j] = a1; sc[2][j] = a2; sc[3][j] = a3;
    lm[0] = fmaxf(lm[0], a0); lm[1] = fmaxf(lm[1], a1);
    lm[2] = fmaxf(lm[2], a2); lm[3] = fmaxf(lm[3], a3);
  }
#pragma unroll
  for (int h = 0; h < 4; ++h) {
    float mm = lm[h];
#pragma unroll
    for (int off = 32; off; off >>= 1) mm = fmaxf(mm, __shfl_xor(mm, off));
    if (lane == 0) wred[h][w] = mm;
  }
  __syncthreads();
  if (t < 4)
    hstat[t] = fmaxf(fmaxf(wred[t][0], wred[t][1]), fmaxf(wred[t][2], wred[t][3]));
  __syncthreads();
  const float m0 = hstat[0], m1 = hstat[1], m2 = hstat[2], m3 = hstat[3];
  float ls[4] = {0.f, 0.f, 0.f, 0.f};
  for (int j = t; j < N; j += 256) {
    float p0 = __expf(sc[0][j] - m0), p1 = __expf(sc[1][j] - m1);
    float p2 = __expf(sc[2][j] - m2), p3 = __expf(sc[3][j] - m3);
    sc[0][j] = p0; sc[1][j] = p1; sc[2][j] = p2; sc[3][j] = p3;
    ls[0] += p0; ls[1] += p1; ls[2] += p2; ls[3] += p3;
  }
#pragma unroll
  for (int h = 0; h < 4; ++h) {
    float ss = ls[h];
#pragma unroll
    for (int off = 32; off; off >>= 1) ss += __shfl_xor(ss, off);
    if (lane == 0) wred[h][w] = ss;
  }
  __syncthreads();
  if (t < 4) hstat[4 + t] = wred[t][0] + wred[t][1] + wred[t][2] + wred[t][3];
  __syncthreads();
  const float i0 = 1.f / hstat[4], i1 = 1.f / hstat[5];
  const float i2 = 1.f / hstat[6], i3 = 1.f / hstat[7];
  for (int j = t; j < N; j += 256)
    meanattn[i * N + j] = 0.25f * (sc[0][j] * i0 + sc[1][j] * i1 + sc[2][j] * i2 + sc[3][j] * i3);
  // msg: wave w handles j in [w*256, w*256+256), lane = output dim (h*16+dd)
  const int hd = lane, h = hd >> 4;
  float acc = 0.f;
  const int j0 = w * 256;
  for (int j = j0; j < j0 + 256; ++j)
    acc += sc[h][j] * qkv[j * 192 + 128 + hd];
  red[t] = acc;
  __syncthreads();
  if (t < 64) {
    const float invh = (t < 16) ? i0 : (t < 32) ? i1 : (t < 48) ? i2 : i3;
    msgv[t] = (red[t] + red[64 + t] + red[128 + t] + red[192 + t]) * invh;
  }
  __syncthreads();
  if (t < 64) {
    float o = out_b[t];
#pragma unroll 8
    for (int k = 0; k < 64; ++k) o += msgv[k] * out_w[k * 64 + t];
    x1[i * D + t] = xn[i * D + t] + o;
  }
}

// ---------------- K3: LN2 + FFN + residual + gate ----------------
__global__ __launch_bounds__(256) void k_ffn_gate(
    const float* __restrict__ x1,
    const float* __restrict__ ln2_g, const float* __restrict__ ln2_b,
    const float* __restrict__ fw1, const float* __restrict__ fb1,
    const float* __restrict__ fw2, const float* __restrict__ fb2,
    const float* __restrict__ gw1, const float* __restrict__ gb1,
    const float* __restrict__ gw2, const float* __restrict__ gb2,
    float* __restrict__ xout, float* __restrict__ gate) {
  const int i = blockIdx.x, t = threadIdx.x;
  __shared__ float xs[64], x1s[64], hs[256];
  if (t < 64) {
    float v = x1[i * 64 + t];
    x1s[t] = v;
    float s = v;
#pragma unroll
    for (int off = 32; off; off >>= 1) s += __shfl_xor(s, off);
    const float m = s * (1.f / 64.f);
    const float dv = v - m;
    float vs = dv * dv;
#pragma unroll
    for (int off = 32; off; off >>= 1) vs += __shfl_xor(vs, off);
    xs[t] = dv * rsqrtf(vs * (1.f / 64.f) + 1e-5f) * ln2_g[t] + ln2_b[t];
  }
  __syncthreads();
  float a = fb1[t];
#pragma unroll 8
  for (int k = 0; k < 64; ++k) a += xs[k] * fw1[k * 256 + t];
  const float ge = 0.5f * a * (1.f + erff(a * 0.70710678118f));
  hs[t] = ge;
  __syncthreads();
  if (t < 64) {
    float o = fb2[t];
#pragma unroll 8
    for (int k = 0; k < 256; ++k) o += hs[k] * fw2[k * 64 + t];
    const float xo = x1s[t] + o;
    xout[i * 64 + t] = xo;
    xs[t] = xo;
  }
  __syncthreads();
  if (t < 64) {
    float a2 = gb1[t];
#pragma unroll 8
    for (int k = 0; k < 64; ++k) a2 += xs[k] * gw1[k * 64 + t];
    const float sg = a2 / (1.f + __expf(-a2));
    float pp = sg * gw2[t];
#pragma unroll
    for (int off = 32; off; off >>= 1) pp += __shfl_xor(pp, off);
    if (t == 0) gate[i] = 1.f / (1.f + __expf(-(pp + gb2[0])));
  }
}

// ---------------- K4: fused pair MLP (edge MLP -> coord MLP -> cw -> delta partial) ----------------
__global__ __launch_bounds__(256) void k_pair(
    const float* __restrict__ coors, const float* __restrict__ meanattn,
    const float* __restrict__ ew1, const float* __restrict__ eb1,
    const float* __restrict__ ew2, const float* __restrict__ eb2,
    const float* __restrict__ cw1, const float* __restrict__ cb1,
    const float* __restrict__ cw2, const float* __restrict__ cb2,
    float* __restrict__ partial) {
  const int i = blockIdx.x;
  const int chunk = blockIdx.y;
  const int t = threadIdx.x;
  const int j = chunk * 256 + t;
  __shared__ float4 W1s[144];    // 9x64
  __shared__ float4 W2s[1024];   // 64x64
  __shared__ float4 C1s[1024];   // 64x64
  __shared__ float b1s[64], b2s[64], cb1s[64], c2s[64];
  __shared__ float rbuf[12];
  {
    float* w1f = (float*)W1s;
    for (int u = t; u < 576; u += 256) w1f[u] = ew1[u];
    float* w2f = (float*)W2s;
    float* c1f = (float*)C1s;
    for (int u = t; u < 4096; u += 256) { w2f[u] = ew2[u]; c1f[u] = cw1[u]; }
    if (t < 64) { b1s[t] = eb1[t]; b2s[t] = eb2[t]; cb1s[t] = cb1[t]; c2s[t] = cw2[t]; }
  }
  __syncthreads();

  const float rx = coors[i * 3 + 0] - coors[j * 3 + 0];
  const float ry = coors[i * 3 + 1] - coors[j * 3 + 1];
  const float rz = coors[i * 3 + 2] - coors[j * 3 + 2];
  const float rd = rx * rx + ry * ry + rz * rz;
  float enc[9];
  enc[0] = __sinf(rd); enc[1] = __sinf(rd * 0.5f); enc[2] = __sinf(rd * 0.25f); enc[3] = __sinf(rd * 0.125f);
  enc[4] = __cosf(rd); enc[5] = __cosf(rd * 0.5f); enc[6] = __cosf(rd * 0.25f); enc[7] = __cosf(rd * 0.125f);
  enc[8] = rd;

  float h1[64];
#pragma unroll
  for (int d = 0; d < 64; ++d) h1[d] = b1s[d];
#pragma unroll
  for (int k = 0; k < 9; ++k) {
    const float ek = enc[k];
#pragma unroll
    for (int d4 = 0; d4 < 16; ++d4) {
      const float4 wv = W1s[k * 16 + d4];
      h1[d4 * 4 + 0] += ek * wv.x; h1[d4 * 4 + 1] += ek * wv.y;
      h1[d4 * 4 + 2] += ek * wv.z; h1[d4 * 4 + 3] += ek * wv.w;
    }
  }
#pragma unroll
  for (int d = 0; d < 64; ++d) { const float v = h1[d]; h1[d] = v / (1.f + __expf(-v)); }

  float e[64];
#pragma unroll
  for (int d = 0; d < 64; ++d) e[d] = b2s[d];
#pragma unroll
  for (int k = 0; k < 64; ++k) {
    const float hk = h1[k];
#pragma unroll
    for (int d4 = 0; d4 < 16; ++d4) {
      const float4 wv = W2s[k * 16 + d4];
      e[d4 * 4 + 0] += hk * wv.x; e[d4 * 4 + 1] += hk * wv.y;
      e[d4 * 4 + 2] += hk * wv.z; e[d4 * 4 + 3] += hk * wv.w;
    }
  }

  float h2[64];
#pragma unroll
  for (int d = 0; d < 64; ++d) h2[d] = cb1s[d];
#pragma unroll
  for (int k = 0; k < 64; ++k) {
    const float ek = e[k];
#pragma unroll
    for (int d4 = 0; d4 < 16; ++d4) {
      const float4 wv = C1s[k * 16 + d4];
      h2[d4 * 4 + 0] += ek * wv.x; h2[d4 * 4 + 1] += ek * wv.y;
      h2[d4 * 4 + 2] += ek * wv.z; h2[d4 * 4 + 3] += ek * wv.w;
    }
  }
  float cw = cb2[0];
#pragma unroll
  for (int d = 0; d < 64; ++d) { const float v = h2[d]; cw += (v / (1.f + __expf(-v))) * c2s[d]; }

  cw *= meanattn[i * N + j];
  float dx = cw * rx, dy = cw * ry, dz = cw * rz;
#pragma unroll
  for (int off = 32; off; off >>= 1) {
    dx += __shfl_xor(dx, off); dy += __shfl_xor(dy, off); dz += __shfl_xor(dz, off);
  }
  const int wv_ = t >> 6;
  if ((t & 63) == 0) { rbuf[wv_ * 3 + 0] = dx; rbuf[wv_ * 3 + 1] = dy; rbuf[wv_ * 3 + 2] = dz; }
  __syncthreads();
  if (t == 0) {
    partial[(i * 4 + chunk) * 3 + 0] = rbuf[0] + rbuf[3] + rbuf[6] + rbuf[9];
    partial[(i * 4 + chunk) * 3 + 1] = rbuf[1] + rbuf[4] + rbuf[7] + rbuf[10];
    partial[(i * 4 + chunk) * 3 + 2] = rbuf[2] + rbuf[5] + rbuf[8] + rbuf[11];
  }
}

// ---------------- K5: reduce partials, apply gate, write coors ----------------
__global__ __launch_bounds__(256) void k_final(
    const float* __restrict__ coors, const float* __restrict__ partial,
    const float* __restrict__ gate, float* __restrict__ outc) {
  const int i = blockIdx.x * 256 + threadIdx.x;
  if (i < N) {
    const float g = gate[i];
    float sx = 0.f, sy = 0.f, sz = 0.f;
#pragma unroll
    for (int c = 0; c < 4; ++c) {
      sx += partial[(i * 4 + c) * 3 + 0];
      sy += partial[(i * 4 + c) * 3 + 1];
      sz += partial[(i * 4 + c) * 3 + 2];
    }
    outc[i * 3 + 0] = coors[i * 3 + 0] + sx * g;
    outc[i * 3 + 1] = coors[i * 3 + 1] + sy * g;
    outc[i * 3 + 2] = coors[i * 3 + 2] + sz * g;
  }
}

extern "C" void kernel_launch(void* const* d_in, const int* in_sizes, int n_in,
                              void* d_out, int out_size, void* d_ws, size_t ws_size,
                              hipStream_t stream) {
  const float* feats = (const float*)d_in[0];
  const float* coors = (const float*)d_in[1];
  const float* qkv_w = (const float*)d_in[2];
  const float* out_w = (const float*)d_in[3];
  const float* out_b = (const float*)d_in[4];
  const float* ew1 = (const float*)d_in[5];
  const float* eb1 = (const float*)d_in[6];
  const float* ew2 = (const float*)d_in[7];
  const float* eb2 = (const float*)d_in[8];
  const float* cw1 = (const float*)d_in[9];
  const float* cb1 = (const float*)d_in[10];
  const float* cw2 = (const float*)d_in[11];
  const float* cb2 = (const float*)d_in[12];
  const float* gw1 = (const float*)d_in[13];
  const float* gb1 = (const float*)d_in[14];
  const float* gw2 = (const float*)d_in[15];
  const float* gb2 = (const float*)d_in[16];
  const float* ln1_g = (const float*)d_in[17];
  const float* ln1_b = (const float*)d_in[18];
  const float* ln2_g = (const float*)d_in[19];
  const float* ln2_b = (const float*)d_in[20];
  const float* fw1 = (const float*)d_in[21];
  const float* fb1 = (const float*)d_in[22];
  const float* fw2 = (const float*)d_in[23];
  const float* fb2 = (const float*)d_in[24];

  float* ws = (float*)d_ws;
  float* xn = ws;                    // 65536
  float* qkv = ws + 65536;           // 196608
  float* x1 = ws + 262144;           // 65536
  float* gate = ws + 327680;         // 1024
  float* partial = ws + 328704;      // 12288
  float* meanattn = ws + 344064;     // 1048576  (~5.6 MB total)

  float* xout = (float*)d_out;
  float* coorout = xout + 65536;

  hipLaunchKernelGGL(k_ln1_qkv, dim3(N), dim3(64), 0, stream, feats, ln1_g, ln1_b, qkv_w, xn, qkv);
  hipLaunchKernelGGL(k_attn, dim3(N), dim3(256), 0, stream, qkv, xn, out_w, out_b, x1, meanattn);
  hipLaunchKernelGGL(k_ffn_gate, dim3(N), dim3(256), 0, stream, x1, ln2_g, ln2_b,
                     fw1, fb1, fw2, fb2, gw1, gb1, gw2, gb2, xout, gate);
  hipLaunchKernelGGL(k_pair, dim3(N, 4), dim3(256), 0, stream, coors, meanattn,
                     ew1, eb1, ew2, eb2, cw1, cb1, cw2, cb2, partial);
  hipLaunchKernelGGL(k_final, dim3(4), dim3(256), 0, stream, coors, partial, gate, coorout);
}

// Round 2
// 167.107 us; speedup vs baseline: 5.7469x; 5.7469x over previous
//
#include <hip/hip_runtime.h>

#define N 1024
#define D 64

typedef __attribute__((ext_vector_type(8))) short bf16x8;
typedef __attribute__((ext_vector_type(4))) float f32x4;

__device__ __forceinline__ unsigned short f2b(float v) {
  unsigned u = __float_as_uint(v);
  u += 0x7fffu + ((u >> 16) & 1u);
  return (unsigned short)(u >> 16);
}
__device__ __forceinline__ unsigned pk2(float a, float b) {
  return (unsigned)f2b(a) | ((unsigned)f2b(b) << 16);
}
__device__ __forceinline__ float silu_f(float x) { return x / (1.f + __expf(-x)); }

// ---------------- K1: LN1 + QKV projection ----------------
__global__ __launch_bounds__(64) void k_ln1_qkv(
    const float* __restrict__ feats, const float* __restrict__ g, const float* __restrict__ b,
    const float* __restrict__ qkv_w, float* __restrict__ xn, float* __restrict__ qkv) {
  const int i = blockIdx.x, t = threadIdx.x;
  float v = feats[i * D + t];
  float s = v;
#pragma unroll
  for (int off = 32; off; off >>= 1) s += __shfl_xor(s, off);
  const float m = s * (1.0f / 64.0f);
  const float dv = v - m;
  float vs = dv * dv;
#pragma unroll
  for (int off = 32; off; off >>= 1) vs += __shfl_xor(vs, off);
  const float var = vs * (1.0f / 64.0f);
  const float xv = dv * rsqrtf(var + 1e-5f) * g[t] + b[t];
  xn[i * D + t] = xv;
  __shared__ float xs[D];
  xs[t] = xv;
  __syncthreads();
#pragma unroll
  for (int c = 0; c < 3; ++c) {
    const int col = t + c * 64;
    float acc = 0.f;
#pragma unroll 8
    for (int k = 0; k < D; ++k) acc += xs[k] * qkv_w[k * 192 + col];
    qkv[i * 192 + col] = acc;
  }
}

// ---------------- K2: attention + mean-attn + out-proj + residual ----------------
__global__ __launch_bounds__(256) void k_attn(
    const float* __restrict__ qkv, const float* __restrict__ xn,
    const float* __restrict__ out_w, const float* __restrict__ out_b,
    float* __restrict__ x1, float* __restrict__ meanattn) {
  const int i = blockIdx.x, t = threadIdx.x;
  const int lane = t & 63, w = t >> 6;
  __shared__ float sc[4][N];
  __shared__ float qi[D];
  __shared__ float wred[4][4];
  __shared__ float hstat[8];
  __shared__ float red[256];
  __shared__ float msgv[64];
  if (t < D) qi[t] = qkv[i * 192 + t];
  __syncthreads();
  float lm[4] = {-1e30f, -1e30f, -1e30f, -1e30f};
  for (int j = t; j < N; j += 256) {
    const float* kj = &qkv[j * 192 + 64];
    float a0 = 0.f, a1 = 0.f, a2 = 0.f, a3 = 0.f;
#pragma unroll
    for (int d = 0; d < 16; ++d) {
      a0 += qi[d] * kj[d];
      a1 += qi[16 + d] * kj[16 + d];
      a2 += qi[32 + d] * kj[32 + d];
      a3 += qi[48 + d] * kj[48 + d];
    }
    a0 *= 0.125f; a1 *= 0.125f; a2 *= 0.125f; a3 *= 0.125f;
    sc[0][j] = a0; sc[1][j] = a1; sc[2][j] = a2; sc[3][j] = a3;
    lm[0] = fmaxf(lm[0], a0); lm[1] = fmaxf(lm[1], a1);
    lm[2] = fmaxf(lm[2], a2); lm[3] = fmaxf(lm[3], a3);
  }
#pragma unroll
  for (int h = 0; h < 4; ++h) {
    float mm = lm[h];
#pragma unroll
    for (int off = 32; off; off >>= 1) mm = fmaxf(mm, __shfl_xor(mm, off));
    if (lane == 0) wred[h][w] = mm;
  }
  __syncthreads();
  if (t < 4)
    hstat[t] = fmaxf(fmaxf(wred[t][0], wred[t][1]), fmaxf(wred[t][2], wred[t][3]));
  __syncthreads();
  const float m0 = hstat[0], m1 = hstat[1], m2 = hstat[2], m3 = hstat[3];
  float ls[4] = {0.f, 0.f, 0.f, 0.f};
  for (int j = t; j < N; j += 256) {
    float p0 = __expf(sc[0][j] - m0), p1 = __expf(sc[1][j] - m1);
    float p2 = __expf(sc[2][j] - m2), p3 = __expf(sc[3][j] - m3);
    sc[0][j] = p0; sc[1][j] = p1; sc[2][j] = p2; sc[3][j] = p3;
    ls[0] += p0; ls[1] += p1; ls[2] += p2; ls[3] += p3;
  }
#pragma unroll
  for (int h = 0; h < 4; ++h) {
    float ss = ls[h];
#pragma unroll
    for (int off = 32; off; off >>= 1) ss += __shfl_xor(ss, off);
    if (lane == 0) wred[h][w] = ss;
  }
  __syncthreads();
  if (t < 4) hstat[4 + t] = wred[t][0] + wred[t][1] + wred[t][2] + wred[t][3];
  __syncthreads();
  const float i0 = 1.f / hstat[4], i1 = 1.f / hstat[5];
  const float i2 = 1.f / hstat[6], i3 = 1.f / hstat[7];
  for (int j = t; j < N; j += 256)
    meanattn[i * N + j] = 0.25f * (sc[0][j] * i0 + sc[1][j] * i1 + sc[2][j] * i2 + sc[3][j] * i3);
  const int hd = lane, h = hd >> 4;
  float acc = 0.f;
  const int j0 = w * 256;
  for (int j = j0; j < j0 + 256; ++j)
    acc += sc[h][j] * qkv[j * 192 + 128 + hd];
  red[t] = acc;
  __syncthreads();
  if (t < 64) {
    const float invh = (t < 16) ? i0 : (t < 32) ? i1 : (t < 48) ? i2 : i3;
    msgv[t] = (red[t] + red[64 + t] + red[128 + t] + red[192 + t]) * invh;
  }
  __syncthreads();
  if (t < 64) {
    float o = out_b[t];
#pragma unroll 8
    for (int k = 0; k < 64; ++k) o += msgv[k] * out_w[k * 64 + t];
    x1[i * D + t] = xn[i * D + t] + o;
  }
}

// ---------------- K3: LN2 + FFN + residual + gate ----------------
__global__ __launch_bounds__(256) void k_ffn_gate(
    const float* __restrict__ x1,
    const float* __restrict__ ln2_g, const float* __restrict__ ln2_b,
    const float* __restrict__ fw1, const float* __restrict__ fb1,
    const float* __restrict__ fw2, const float* __restrict__ fb2,
    const float* __restrict__ gw1, const float* __restrict__ gb1,
    const float* __restrict__ gw2, const float* __restrict__ gb2,
    float* __restrict__ xout, float* __restrict__ gate) {
  const int i = blockIdx.x, t = threadIdx.x;
  __shared__ float xs[64], x1s[64], hs[256];
  if (t < 64) {
    float v = x1[i * 64 + t];
    x1s[t] = v;
    float s = v;
#pragma unroll
    for (int off = 32; off; off >>= 1) s += __shfl_xor(s, off);
    const float m = s * (1.f / 64.f);
    const float dv = v - m;
    float vs = dv * dv;
#pragma unroll
    for (int off = 32; off; off >>= 1) vs += __shfl_xor(vs, off);
    xs[t] = dv * rsqrtf(vs * (1.f / 64.f) + 1e-5f) * ln2_g[t] + ln2_b[t];
  }
  __syncthreads();
  float a = fb1[t];
#pragma unroll 8
  for (int k = 0; k < 64; ++k) a += xs[k] * fw1[k * 256 + t];
  const float ge = 0.5f * a * (1.f + erff(a * 0.70710678118f));
  hs[t] = ge;
  __syncthreads();
  if (t < 64) {
    float o = fb2[t];
#pragma unroll 8
    for (int k = 0; k < 256; ++k) o += hs[k] * fw2[k * 64 + t];
    const float xo = x1s[t] + o;
    xout[i * 64 + t] = xo;
    xs[t] = xo;
  }
  __syncthreads();
  if (t < 64) {
    float a2 = gb1[t];
#pragma unroll 8
    for (int k = 0; k < 64; ++k) a2 += xs[k] * gw1[k * 64 + t];
    const float sg = a2 / (1.f + __expf(-a2));
    float pp = sg * gw2[t];
#pragma unroll
    for (int off = 32; off; off >>= 1) pp += __shfl_xor(pp, off);
    if (t == 0) gate[i] = 1.f / (1.f + __expf(-(pp + gb2[0])));
  }
}

// ---------------- K_prep: pack transposed bf16 weight fragments ----------------
// frag f, lane l, elem e. f 0..3 = W1T (mt=f, ks=0, k<9 real), 4..11 = W2T, 12..19 = C1T
__global__ __launch_bounds__(256) void k_prep(
    const float* __restrict__ ew1, const float* __restrict__ ew2,
    const float* __restrict__ cw1, unsigned short* __restrict__ pw) {
  const int t = threadIdx.x;
  for (int idx = t; idx < 20 * 512; idx += 256) {
    const int e = idx & 7, l = (idx >> 3) & 63, f = idx >> 9;
    const int l15 = l & 15, lg = l >> 4;
    float v;
    if (f < 4) {
      const int d = f * 16 + l15, k = lg * 8 + e;
      v = (k < 9) ? ew1[k * 64 + d] : 0.f;
    } else if (f < 12) {
      const int g = f - 4, d = (g >> 1) * 16 + l15, k = (g & 1) * 32 + lg * 8 + e;
      v = ew2[k * 64 + d];
    } else {
      const int g = f - 12, d = (g >> 1) * 16 + l15, k = (g & 1) * 32 + lg * 8 + e;
      v = cw1[k * 64 + d];
    }
    pw[idx] = f2b(v);
  }
}

// ---------------- K4: MFMA pair pipeline ----------------
// Transposed formulation: M = feature dim (A = weights, in VGPRs), N = pair index j.
// Per wave: 32-j panel; enc(K=32 pad) -> h1 -> e -> h2; cw dot + delta in registers.
__global__ __launch_bounds__(256, 2) void k_pair(
    const float* __restrict__ coors, const float* __restrict__ meanattn,
    const unsigned short* __restrict__ pw,
    const float* __restrict__ eb1, const float* __restrict__ eb2,
    const float* __restrict__ cb1, const float* __restrict__ c2g,
    const float* __restrict__ cb2, const float* __restrict__ gate,
    float* __restrict__ outc) {
  const int i = blockIdx.x;
  const int t = threadIdx.x;
  const int w = t >> 6;
  const int lane = t & 63;
  const int l15 = lane & 15;
  const int lg = lane >> 4;

  __shared__ __align__(16) unsigned short enc_s[4][32][64];
  __shared__ __align__(16) unsigned short h1_s[4][32][64];
  __shared__ __align__(16) unsigned short e_s[4][32][64];
  __shared__ float4 relma[4][32];
  __shared__ float redb[4][3];

  // weight fragments -> registers (80 VGPR)
  bf16x8 wf[20];
#pragma unroll
  for (int f = 0; f < 20; ++f)
    wf[f] = *(const bf16x8*)&pw[(f * 64 + lane) * 8];

  // biases + c2, indexed d = mt*16 + lg*4 + r
  float b1v[16], b2v[16], b3v[16], c2v[16];
#pragma unroll
  for (int mt = 0; mt < 4; ++mt)
#pragma unroll
    for (int r = 0; r < 4; ++r) {
      const int d = mt * 16 + lg * 4 + r;
      b1v[mt * 4 + r] = eb1[d];
      b2v[mt * 4 + r] = eb2[d];
      b3v[mt * 4 + r] = cb1[d];
      c2v[mt * 4 + r] = c2g[d];
    }
  const float cb2q = cb2[0] * 0.25f;
  const float cix = coors[i * 3 + 0], ciy = coors[i * 3 + 1], ciz = coors[i * 3 + 2];

  // zero-init enc k=12..31 (written once; k0..11 rewritten every chunk)
  if (lane < 32) {
    const int j = lane;
    unsigned short* rp = &enc_s[w][j][0];
    *(uint4*)&rp[(2 ^ (j & 7)) * 8] = make_uint4(0, 0, 0, 0);
    *(uint4*)&rp[(3 ^ (j & 7)) * 8] = make_uint4(0, 0, 0, 0);
    *(uint2*)&rp[(1 ^ (j & 7)) * 8 + 4] = make_uint2(0, 0);
  }

  float dx = 0.f, dy = 0.f, dz = 0.f;
  f32x4 acc[4][2];

  for (int c = 0; c < 8; ++c) {
    // ---- enc + rel*ma ----
    if (lane < 32) {
      const int j = lane;
      const int jg = c * 128 + w * 32 + j;
      const float rx = cix - coors[jg * 3 + 0];
      const float ry = ciy - coors[jg * 3 + 1];
      const float rz = ciz - coors[jg * 3 + 2];
      const float rd = rx * rx + ry * ry + rz * rz;
      const float ma = meanattn[i * N + jg];
      relma[w][j] = make_float4(ma * rx, ma * ry, ma * rz, 0.f);
      const unsigned p0 = pk2(__sinf(rd), __sinf(rd * 0.5f));
      const unsigned p1 = pk2(__sinf(rd * 0.25f), __sinf(rd * 0.125f));
      const unsigned p2 = pk2(__cosf(rd), __cosf(rd * 0.5f));
      const unsigned p3 = pk2(__cosf(rd * 0.25f), __cosf(rd * 0.125f));
      unsigned short* rp = &enc_s[w][j][0];
      *(uint4*)&rp[(0 ^ (j & 7)) * 8] = make_uint4(p0, p1, p2, p3);
      *(uint2*)&rp[(1 ^ (j & 7)) * 8] = make_uint2(pk2(rd, 0.f), 0u);
    }

    // ---- GEMM1: h1T = W1T @ encT  (K=32) ----
#pragma unroll
    for (int mt = 0; mt < 4; ++mt)
#pragma unroll
      for (int nt = 0; nt < 2; ++nt)
        acc[mt][nt] = (f32x4){b1v[mt * 4 + 0], b1v[mt * 4 + 1], b1v[mt * 4 + 2], b1v[mt * 4 + 3]};
    {
      const int j0 = l15, j1 = 16 + l15;
      bf16x8 bf0 = *(const bf16x8*)&enc_s[w][j0][(lg ^ (j0 & 7)) * 8];
      bf16x8 bf1 = *(const bf16x8*)&enc_s[w][j1][(lg ^ (j1 & 7)) * 8];
#pragma unroll
      for (int mt = 0; mt < 4; ++mt) {
        acc[mt][0] = __builtin_amdgcn_mfma_f32_16x16x32_bf16(wf[mt], bf0, acc[mt][0], 0, 0, 0);
        acc[mt][1] = __builtin_amdgcn_mfma_f32_16x16x32_bf16(wf[mt], bf1, acc[mt][1], 0, 0, 0);
      }
    }
    // silu -> h1_s [j][d] swizzled
#pragma unroll
    for (int mt = 0; mt < 4; ++mt)
#pragma unroll
      for (int nt = 0; nt < 2; ++nt) {
        const f32x4 a = acc[mt][nt];
        const unsigned lo = pk2(silu_f(a[0]), silu_f(a[1]));
        const unsigned hi = pk2(silu_f(a[2]), silu_f(a[3]));
        const int j = nt * 16 + l15;
        const int g = mt * 2 + (lg >> 1);
        *(uint2*)&h1_s[w][j][((g ^ (j & 7)) * 8) + (lg & 1) * 4] = make_uint2(lo, hi);
      }

    // ---- GEMM2: eT = W2T @ h1T  (K=64) ----
#pragma unroll
    for (int mt = 0; mt < 4; ++mt)
#pragma unroll
      for (int nt = 0; nt < 2; ++nt)
        acc[mt][nt] = (f32x4){b2v[mt * 4 + 0], b2v[mt * 4 + 1], b2v[mt * 4 + 2], b2v[mt * 4 + 3]};
#pragma unroll
    for (int ks = 0; ks < 2; ++ks) {
      const int gi = ks * 4 + lg;
      const int j0 = l15, j1 = 16 + l15;
      bf16x8 bf0 = *(const bf16x8*)&h1_s[w][j0][(gi ^ (j0 & 7)) * 8];
      bf16x8 bf1 = *(const bf16x8*)&h1_s[w][j1][(gi ^ (j1 & 7)) * 8];
#pragma unroll
      for (int mt = 0; mt < 4; ++mt) {
        acc[mt][0] = __builtin_amdgcn_mfma_f32_16x16x32_bf16(wf[4 + mt * 2 + ks], bf0, acc[mt][0], 0, 0, 0);
        acc[mt][1] = __builtin_amdgcn_mfma_f32_16x16x32_bf16(wf[4 + mt * 2 + ks], bf1, acc[mt][1], 0, 0, 0);
      }
    }
    // e (no activation) -> e_s
#pragma unroll
    for (int mt = 0; mt < 4; ++mt)
#pragma unroll
      for (int nt = 0; nt < 2; ++nt) {
        const f32x4 a = acc[mt][nt];
        const unsigned lo = pk2(a[0], a[1]);
        const unsigned hi = pk2(a[2], a[3]);
        const int j = nt * 16 + l15;
        const int g = mt * 2 + (lg >> 1);
        *(uint2*)&e_s[w][j][((g ^ (j & 7)) * 8) + (lg & 1) * 4] = make_uint2(lo, hi);
      }

    // ---- GEMM3: h2T = C1T @ eT  (K=64) ----
#pragma unroll
    for (int mt = 0; mt < 4; ++mt)
#pragma unroll
      for (int nt = 0; nt < 2; ++nt)
        acc[mt][nt] = (f32x4){b3v[mt * 4 + 0], b3v[mt * 4 + 1], b3v[mt * 4 + 2], b3v[mt * 4 + 3]};
#pragma unroll
    for (int ks = 0; ks < 2; ++ks) {
      const int gi = ks * 4 + lg;
      const int j0 = l15, j1 = 16 + l15;
      bf16x8 bf0 = *(const bf16x8*)&e_s[w][j0][(gi ^ (j0 & 7)) * 8];
      bf16x8 bf1 = *(const bf16x8*)&e_s[w][j1][(gi ^ (j1 & 7)) * 8];
#pragma unroll
      for (int mt = 0; mt < 4; ++mt) {
        acc[mt][0] = __builtin_amdgcn_mfma_f32_16x16x32_bf16(wf[12 + mt * 2 + ks], bf0, acc[mt][0], 0, 0, 0);
        acc[mt][1] = __builtin_amdgcn_mfma_f32_16x16x32_bf16(wf[12 + mt * 2 + ks], bf1, acc[mt][1], 0, 0, 0);
      }
    }

    // ---- epilogue: cw partial dot + delta accumulate ----
#pragma unroll
    for (int nt = 0; nt < 2; ++nt) {
      float cwp = cb2q;
#pragma unroll
      for (int mt = 0; mt < 4; ++mt) {
        const f32x4 a = acc[mt][nt];
#pragma unroll
        for (int r = 0; r < 4; ++r) cwp += silu_f(a[r]) * c2v[mt * 4 + r];
      }
      const float4 rm = relma[w][nt * 16 + l15];
      dx += cwp * rm.x;
      dy += cwp * rm.y;
      dz += cwp * rm.z;
    }
  }

  // reduce delta across wave, then block
#pragma unroll
  for (int off = 1; off < 64; off <<= 1) {
    dx += __shfl_xor(dx, off);
    dy += __shfl_xor(dy, off);
    dz += __shfl_xor(dz, off);
  }
  if (lane == 0) { redb[w][0] = dx; redb[w][1] = dy; redb[w][2] = dz; }
  __syncthreads();
  if (t == 0) {
    const float gg = gate[i];
    const float sx = redb[0][0] + redb[1][0] + redb[2][0] + redb[3][0];
    const float sy = redb[0][1] + redb[1][1] + redb[2][1] + redb[3][1];
    const float sz = redb[0][2] + redb[1][2] + redb[2][2] + redb[3][2];
    outc[i * 3 + 0] = cix + sx * gg;
    outc[i * 3 + 1] = ciy + sy * gg;
    outc[i * 3 + 2] = ciz + sz * gg;
  }
}

extern "C" void kernel_launch(void* const* d_in, const int* in_sizes, int n_in,
                              void* d_out, int out_size, void* d_ws, size_t ws_size,
                              hipStream_t stream) {
  const float* feats = (const float*)d_in[0];
  const float* coors = (const float*)d_in[1];
  const float* qkv_w = (const float*)d_in[2];
  const float* out_w = (const float*)d_in[3];
  const float* out_b = (const float*)d_in[4];
  const float* ew1 = (const float*)d_in[5];
  const float* eb1 = (const float*)d_in[6];
  const float* ew2 = (const float*)d_in[7];
  const float* eb2 = (const float*)d_in[8];
  const float* cw1 = (const float*)d_in[9];
  const float* cb1 = (const float*)d_in[10];
  const float* cw2 = (const float*)d_in[11];
  const float* cb2 = (const float*)d_in[12];
  const float* gw1 = (const float*)d_in[13];
  const float* gb1 = (const float*)d_in[14];
  const float* gw2 = (const float*)d_in[15];
  const float* gb2 = (const float*)d_in[16];
  const float* ln1_g = (const float*)d_in[17];
  const float* ln1_b = (const float*)d_in[18];
  const float* ln2_g = (const float*)d_in[19];
  const float* ln2_b = (const float*)d_in[20];
  const float* fw1 = (const float*)d_in[21];
  const float* fb1 = (const float*)d_in[22];
  const float* fw2 = (const float*)d_in[23];
  const float* fb2 = (const float*)d_in[24];

  float* ws = (float*)d_ws;
  float* xn = ws;                         // 65536
  float* qkv = ws + 65536;                // 196608
  float* x1 = ws + 262144;                // 65536
  float* gate = ws + 327680;              // 1024
  unsigned short* pw = (unsigned short*)(ws + 328704);  // 10240 ushort = 5120 floats
  float* meanattn = ws + 333824;          // 1048576

  float* xout = (float*)d_out;
  float* coorout = xout + 65536;

  hipLaunchKernelGGL(k_ln1_qkv, dim3(N), dim3(64), 0, stream, feats, ln1_g, ln1_b, qkv_w, xn, qkv);
  hipLaunchKernelGGL(k_prep, dim3(1), dim3(256), 0, stream, ew1, ew2, cw1, pw);
  hipLaunchKernelGGL(k_attn, dim3(N), dim3(256), 0, stream, qkv, xn, out_w, out_b, x1, meanattn);
  hipLaunchKernelGGL(k_ffn_gate, dim3(N), dim3(256), 0, stream, x1, ln2_g, ln2_b,
                     fw1, fb1, fw2, fb2, gw1, gb1, gw2, gb2, xout, gate);
  hipLaunchKernelGGL(k_pair, dim3(N), dim3(256), 0, stream, coors, meanattn, pw,
                     eb1, eb2, cb1, cw2, cb2, gate, coorout);
}